// Round 2
// baseline (99.660 us; speedup 1.0000x reference)
//
#include <hip/hip_runtime.h>
#include <math.h>

// Ordinal regression loss: mean over (B, K=4) of
//   max(x,0) - x*[k < label] + log1p(exp(-|x|))
// Memory-bound streaming reduction, single fused kernel with
// last-block-done final reduce (deterministic, no fp atomics).

#define KDIM 4
#define BLOCK 256
#define GRID 2048

__device__ __forceinline__ float row_loss(float4 x, int lab) {
    float xs[KDIM] = {x.x, x.y, x.z, x.w};
    float acc = 0.0f;
#pragma unroll
    for (int k = 0; k < KDIM; ++k) {
        float v = xs[k];
        float t = (k < lab) ? 1.0f : 0.0f;
        float a = fabsf(v);
        // softplus(-a) = log(1 + exp(-a)), a >= 0 so exp(-a) <= 1 (stable)
        float sp = __logf(1.0f + __expf(-a));
        acc += fmaxf(v, 0.0f) - v * t + sp;
    }
    return acc;
}

__global__ __launch_bounds__(BLOCK) void ordloss_fused(
    const float4* __restrict__ logits,   // B rows, one float4 per row (K=4)
    const int* __restrict__ labels,      // B int32
    float* __restrict__ partial,         // GRID floats (in d_ws)
    unsigned int* __restrict__ counter,  // 1 uint (in d_ws), zeroed per call
    float* __restrict__ out,             // 1 float
    int B, float inv_count)
{
    int tid = blockIdx.x * BLOCK + threadIdx.x;
    const int stride = GRID * BLOCK;

    const int pairs = B >> 1;
    float acc = 0.0f;
    for (int i = tid; i < pairs; i += stride) {
        // two consecutive rows: 32 B of logits + 8 B of labels per lane
        float4 x0 = logits[2 * i];
        float4 x1 = logits[2 * i + 1];
        int2 lab = ((const int2*)labels)[i];
        acc += row_loss(x0, lab.x);
        acc += row_loss(x1, lab.y);
    }
    if ((B & 1) && tid == 0) {
        acc += row_loss(logits[B - 1], labels[B - 1]);
    }

    // wave64 shuffle reduction
#pragma unroll
    for (int off = 32; off > 0; off >>= 1)
        acc += __shfl_down(acc, off, 64);

    __shared__ float wsum[BLOCK / 64];
    __shared__ bool is_last;
    int lane = threadIdx.x & 63;
    int wid  = threadIdx.x >> 6;
    if (lane == 0) wsum[wid] = acc;
    __syncthreads();
    if (threadIdx.x == 0) {
        float s = wsum[0] + wsum[1] + wsum[2] + wsum[3];
        partial[blockIdx.x] = s;
        __threadfence();                       // publish partial before ticket
        unsigned int done = atomicAdd(counter, 1u);
        is_last = (done == GRID - 1);
    }
    __syncthreads();

    if (is_last) {
        __threadfence();                       // acquire: see all partials
        float facc = 0.0f;
        for (int i = threadIdx.x; i < GRID; i += BLOCK)
            facc += partial[i];
#pragma unroll
        for (int off = 32; off > 0; off >>= 1)
            facc += __shfl_down(facc, off, 64);
        if (lane == 0) wsum[wid] = facc;
        __syncthreads();
        if (threadIdx.x == 0) {
            float s = wsum[0] + wsum[1] + wsum[2] + wsum[3];
            out[0] = s * inv_count;
        }
    }
}

extern "C" void kernel_launch(void* const* d_in, const int* in_sizes, int n_in,
                              void* d_out, int out_size, void* d_ws, size_t ws_size,
                              hipStream_t stream) {
    const float4* logits = (const float4*)d_in[0];
    const int*    labels = (const int*)d_in[1];
    float*        out    = (float*)d_out;
    float*        partial = (float*)d_ws;                  // GRID floats
    unsigned int* counter = (unsigned int*)((char*)d_ws + GRID * sizeof(float));

    int B = in_sizes[1];  // labels count = rows
    float inv_count = 1.0f / ((float)B * (float)KDIM);

    hipMemsetAsync(counter, 0, sizeof(unsigned int), stream);
    ordloss_fused<<<GRID, BLOCK, 0, stream>>>(logits, labels, partial, counter,
                                              out, B, inv_count);
}

// Round 3
// 39.738 us; speedup vs baseline: 2.5079x; 2.5079x over previous
//
#include <hip/hip_runtime.h>
#include <math.h>

// Ordinal regression loss: mean over (B, K=4) of
//   max(x,0) - x*[k < label] + log1p(exp(-|x|))
// Memory-bound streaming reduction. Two-pass deterministic reduce.
// Round 3: unroll-by-4 at grid-stride offsets (keeps per-instruction
// coalescing perfect, 4x memory-level parallelism per thread).

#define KDIM 4
#define BLOCK 256
#define GRID 2048

__device__ __forceinline__ float row_loss(float4 x, int lab) {
    float xs[KDIM] = {x.x, x.y, x.z, x.w};
    float acc = 0.0f;
#pragma unroll
    for (int k = 0; k < KDIM; ++k) {
        float v = xs[k];
        float t = (k < lab) ? 1.0f : 0.0f;
        float a = fabsf(v);
        // softplus(-a) = log(1 + exp(-a)), a >= 0 so exp(-a) <= 1 (stable)
        float sp = __logf(1.0f + __expf(-a));
        acc += fmaxf(v, 0.0f) - v * t + sp;
    }
    return acc;
}

__global__ __launch_bounds__(BLOCK) void ordloss_partial(
    const float4* __restrict__ logits,   // B rows, one float4 per row (K=4)
    const int* __restrict__ labels,      // B int32
    float* __restrict__ partial,         // GRID floats
    int B)
{
    int tid = blockIdx.x * BLOCK + threadIdx.x;
    const int stride = GRID * BLOCK;

    float acc = 0.0f;
    int i = tid;
    // Main loop: 4 independent, perfectly-coalesced row loads in flight.
    for (; i + 3 * stride < B; i += 4 * stride) {
        float4 x0 = logits[i];
        float4 x1 = logits[i + stride];
        float4 x2 = logits[i + 2 * stride];
        float4 x3 = logits[i + 3 * stride];
        int l0 = labels[i];
        int l1 = labels[i + stride];
        int l2 = labels[i + 2 * stride];
        int l3 = labels[i + 3 * stride];
        acc += row_loss(x0, l0);
        acc += row_loss(x1, l1);
        acc += row_loss(x2, l2);
        acc += row_loss(x3, l3);
    }
    for (; i < B; i += stride)
        acc += row_loss(logits[i], labels[i]);

    // wave64 shuffle reduction
#pragma unroll
    for (int off = 32; off > 0; off >>= 1)
        acc += __shfl_down(acc, off, 64);

    __shared__ float wsum[BLOCK / 64];
    int lane = threadIdx.x & 63;
    int wid  = threadIdx.x >> 6;
    if (lane == 0) wsum[wid] = acc;
    __syncthreads();
    if (threadIdx.x == 0) {
        float s = 0.0f;
#pragma unroll
        for (int w = 0; w < BLOCK / 64; ++w) s += wsum[w];
        partial[blockIdx.x] = s;
    }
}

__global__ __launch_bounds__(BLOCK) void ordloss_final(
    const float* __restrict__ partial, int n,
    float* __restrict__ out, float inv_count)
{
    float acc = 0.0f;
    for (int i = threadIdx.x; i < n; i += BLOCK) acc += partial[i];
#pragma unroll
    for (int off = 32; off > 0; off >>= 1)
        acc += __shfl_down(acc, off, 64);

    __shared__ float wsum[BLOCK / 64];
    int lane = threadIdx.x & 63;
    int wid  = threadIdx.x >> 6;
    if (lane == 0) wsum[wid] = acc;
    __syncthreads();
    if (threadIdx.x == 0) {
        float s = 0.0f;
#pragma unroll
        for (int w = 0; w < BLOCK / 64; ++w) s += wsum[w];
        out[0] = s * inv_count;
    }
}

extern "C" void kernel_launch(void* const* d_in, const int* in_sizes, int n_in,
                              void* d_out, int out_size, void* d_ws, size_t ws_size,
                              hipStream_t stream) {
    const float4* logits = (const float4*)d_in[0];
    const int*    labels = (const int*)d_in[1];
    float*        out    = (float*)d_out;
    float*        partial = (float*)d_ws;   // GRID floats = 8 KiB

    int B = in_sizes[1];  // labels count = rows
    float inv_count = 1.0f / ((float)B * (float)KDIM);

    ordloss_partial<<<GRID, BLOCK, 0, stream>>>(logits, labels, partial, B);
    ordloss_final<<<1, BLOCK, 0, stream>>>(partial, GRID, out, inv_count);
}